// Round 8
// baseline (94.500 us; speedup 1.0000x reference)
//
#include <hip/hip_runtime.h>
#include <math.h>

// Problem constants (from reference): B=8, S=4096, D=1024, fp32 in/out.
#define B_    8
#define S_    4096
#define D_    1024
#define RPW   16                 // rows per wave
#define BPB   64                 // blocks per batch (S / (4 waves * RPW))
#define NBLK  (B_ * BPB)         // 512 blocks == 512 merged partials
#define NPB2  BPB                // partials per batch after in-block merge

// ws layout (float offsets)
#define PM_OFF    0                       // [NBLK] per-block max
#define PL_OFF    (PM_OFF + NBLK)         // [NBLK] per-block denom
#define CNT_OFF   1024                    // [B_] int counters (byte off 4096)
#define PACC_OFF  16384                   // [NBLK * D_]  (64KB aligned)

// ---------------------------------------------------------------------------
// Single fused kernel.
//  Phase 1 (all 512 blocks): stream 64 rows/block with the proven R5 core
//   (A/B register double-buffer, launch_bounds(256,2) so the ~190-reg live
//   set gets a 256-VGPR budget -- R4/R5 A/B proved the no-lb 64-VGPR clamp
//   spills everything). 4 waves merge (m,l,acc) in LDS -> 1 partial/block.
//  Publish: __threadfence() + atomicAdd(cnt[b]) (device scope).
//  Phase 2 (last block of each batch only): acquire fence, then fixed-order
//   combine of the batch's 64 partials -> out row. Deterministic: the set of
//   partials and the reduction order are fixed; only WHICH block runs it
//   varies. Counters are re-zeroed by a memset node every call.
// ---------------------------------------------------------------------------
__global__ __launch_bounds__(256, 2) void attn_fused(
    const float* __restrict__ data, const float* __restrict__ crit,
    float* __restrict__ pm, float* __restrict__ pl, float* __restrict__ pacc,
    int* __restrict__ cnt, float* __restrict__ out)
{
    const int lane = threadIdx.x & 63;
    const int wid  = threadIdx.x >> 6;
    const int b    = blockIdx.x >> 6;           // / BPB
    const int blkb = blockIdx.x & 63;           // % BPB
    const int s0   = blkb * 64 + wid * RPW;     // this wave's first row

    const float4* c4p = reinterpret_cast<const float4*>(crit + (size_t)b * D_);
    float4 cc[4];
    cc[0] = c4p[0 * 64 + lane];
    cc[1] = c4p[1 * 64 + lane];
    cc[2] = c4p[2 * 64 + lane];
    cc[3] = c4p[3 * 64 + lane];

    const float4* dp = reinterpret_cast<const float4*>(data)
                     + (size_t)(b * S_ + s0) * (D_ / 4);

    float4 a0 = {0,0,0,0}, a1 = {0,0,0,0}, a2 = {0,0,0,0}, a3 = {0,0,0,0};
    float m = -INFINITY, l = 0.f;

    float4 vA[4][4], vB[4][4];

    #define LOADG(V, G)                                                        \
        {                                                                      \
            _Pragma("unroll")                                                  \
            for (int r = 0; r < 4; ++r) {                                      \
                const float4* rp = dp + (size_t)((G) * 4 + r) * (D_ / 4);      \
                V[r][0] = rp[0 * 64 + lane];                                   \
                V[r][1] = rp[1 * 64 + lane];                                   \
                V[r][2] = rp[2 * 64 + lane];                                   \
                V[r][3] = rp[3 * 64 + lane];                                   \
            }                                                                  \
        }

    // Accumulator update: direct named variables, compile-time fields only
    // (R3 lesson: no pointers-to-local -> no blocked SROA).
    #define UPD1(A, V, J, F)                                                   \
        A.F = fmaf(A.F, scale, fmaf(p0, V[0][J].F, fmaf(p1, V[1][J].F,         \
              fmaf(p2, V[2][J].F, p3 * V[3][J].F))));
    #define UPDA(A, V, J)                                                      \
        UPD1(A, V, J, x) UPD1(A, V, J, y) UPD1(A, V, J, z) UPD1(A, V, J, w)

    // COMPUTE: dot -> pack-4 cross-lane reduce (11 DS ops) -> online softmax.
    #define COMPUTE(V)                                                         \
        {                                                                      \
            float sc[4];                                                       \
            _Pragma("unroll")                                                  \
            for (int r = 0; r < 4; ++r) {                                      \
                float p = 0.f;                                                 \
                _Pragma("unroll")                                              \
                for (int j = 0; j < 4; ++j) {                                  \
                    p = fmaf(V[r][j].x, cc[j].x, p);                           \
                    p = fmaf(V[r][j].y, cc[j].y, p);                           \
                    p = fmaf(V[r][j].z, cc[j].z, p);                           \
                    p = fmaf(V[r][j].w, cc[j].w, p);                           \
                }                                                              \
                sc[r] = p;                                                     \
            }                                                                  \
            const bool o1 = (lane & 1);                                        \
            float v01 = o1 ? sc[1] : sc[0], w01 = o1 ? sc[0] : sc[1];          \
            float v23 = o1 ? sc[3] : sc[2], w23 = o1 ? sc[2] : sc[3];          \
            v01 += __shfl_xor(w01, 1, 64);                                     \
            v23 += __shfl_xor(w23, 1, 64);                                     \
            const bool o2 = (lane & 2);                                        \
            float av = o2 ? v23 : v01, bv = o2 ? v01 : v23;                    \
            av += __shfl_xor(bv, 2, 64);                                       \
            av += __shfl_xor(av, 4, 64);                                       \
            av += __shfl_xor(av, 8, 64);                                       \
            av += __shfl_xor(av, 16, 64);                                      \
            av += __shfl_xor(av, 32, 64);                                      \
            const int base = lane & ~3;                                        \
            const float s0v = __shfl(av, base + 0, 64);                        \
            const float s1v = __shfl(av, base + 1, 64);                        \
            const float s2v = __shfl(av, base + 2, 64);                        \
            const float s3v = __shfl(av, base + 3, 64);                        \
            const float gm = fmaxf(fmaxf(s0v, s1v), fmaxf(s2v, s3v));          \
            const float mn = fmaxf(m, gm);                                     \
            const float scale = __expf(m - mn);                                \
            const float p0 = __expf(s0v - mn);                                 \
            const float p1 = __expf(s1v - mn);                                 \
            const float p2 = __expf(s2v - mn);                                 \
            const float p3 = __expf(s3v - mn);                                 \
            l = fmaf(l, scale, p0 + p1 + p2 + p3);                             \
            UPDA(a0, V, 0) UPDA(a1, V, 1) UPDA(a2, V, 2) UPDA(a3, V, 3)        \
            m = mn;                                                            \
        }

    LOADG(vA, 0)
    LOADG(vB, 1)
    COMPUTE(vA)
    LOADG(vA, 2)
    COMPUTE(vB)
    LOADG(vB, 3)
    COMPUTE(vA)
    COMPUTE(vB)

    #undef LOADG
    #undef COMPUTE
    #undef UPDA
    #undef UPD1

    // ---- in-block merge of the 4 waves' (m, l, acc) via LDS ----
    __shared__ float lds_acc[4][D_];
    __shared__ float lds_m[4], lds_l[4];
    __shared__ int   lds_last;

    float4* lp = reinterpret_cast<float4*>(&lds_acc[wid][0]);
    lp[0 * 64 + lane] = a0;
    lp[1 * 64 + lane] = a1;
    lp[2 * 64 + lane] = a2;
    lp[3 * 64 + lane] = a3;
    if (lane == 0) { lds_m[wid] = m; lds_l[wid] = l; }
    __syncthreads();

    const int t = threadIdx.x;           // thread owns columns 4t..4t+3
    {
        const float m0 = lds_m[0], m1 = lds_m[1], m2 = lds_m[2], m3 = lds_m[3];
        const float ms = fmaxf(fmaxf(m0, m1), fmaxf(m2, m3));
        const float f0 = __expf(m0 - ms);
        const float f1 = __expf(m1 - ms);
        const float f2 = __expf(m2 - ms);
        const float f3 = __expf(m3 - ms);

        const float4 w0 = reinterpret_cast<const float4*>(&lds_acc[0][0])[t];
        const float4 w1 = reinterpret_cast<const float4*>(&lds_acc[1][0])[t];
        const float4 w2 = reinterpret_cast<const float4*>(&lds_acc[2][0])[t];
        const float4 w3 = reinterpret_cast<const float4*>(&lds_acc[3][0])[t];

        float4 r;
        r.x = fmaf(f0, w0.x, fmaf(f1, w1.x, fmaf(f2, w2.x, f3 * w3.x)));
        r.y = fmaf(f0, w0.y, fmaf(f1, w1.y, fmaf(f2, w2.y, f3 * w3.y)));
        r.z = fmaf(f0, w0.z, fmaf(f1, w1.z, fmaf(f2, w2.z, f3 * w3.z)));
        r.w = fmaf(f0, w0.w, fmaf(f1, w1.w, fmaf(f2, w2.w, f3 * w3.w)));

        reinterpret_cast<float4*>(pacc)[(size_t)blockIdx.x * (D_ / 4) + t] = r;
        if (t == 0) {
            pm[blockIdx.x] = ms;
            pl[blockIdx.x] = fmaf(f0, lds_l[0], fmaf(f1, lds_l[1],
                             fmaf(f2, lds_l[2], f3 * lds_l[3])));
        }
    }

    // ---- publish: device-scope release, count arrivals for this batch ----
    __threadfence();                       // my writes -> visible device-wide
    __syncthreads();                       // all threads' fences done
    if (t == 0) {
        const int old = atomicAdd(&cnt[b], 1);   // device-scope by default
        lds_last = (old == BPB - 1);
    }
    __syncthreads();
    if (!lds_last) return;

    // ---- phase 2: this block is last for batch b -> combine 64 partials ----
    __threadfence();                       // acquire: invalidate stale caches

    const int c0 = b * NPB2;

    float mstar = -INFINITY;
    #pragma unroll 8
    for (int k = 0; k < NPB2; ++k) mstar = fmaxf(mstar, pm[c0 + k]);

    float4 ps0 = {0,0,0,0}, ps1 = {0,0,0,0}, ps2 = {0,0,0,0}, ps3 = {0,0,0,0};
    float  L0 = 0.f, L1 = 0.f, L2 = 0.f, L3 = 0.f;
    const float4* pa4 = reinterpret_cast<const float4*>(pacc);
    #pragma unroll 4
    for (int k = 0; k < NPB2; k += 4) {
        const float fa = __expf(pm[c0 + k + 0] - mstar);
        const float fb = __expf(pm[c0 + k + 1] - mstar);
        const float fc = __expf(pm[c0 + k + 2] - mstar);
        const float fd = __expf(pm[c0 + k + 3] - mstar);
        const float4 va = pa4[(size_t)(c0 + k + 0) * (D_ / 4) + t];
        const float4 vb = pa4[(size_t)(c0 + k + 1) * (D_ / 4) + t];
        const float4 vc = pa4[(size_t)(c0 + k + 2) * (D_ / 4) + t];
        const float4 vd = pa4[(size_t)(c0 + k + 3) * (D_ / 4) + t];
        ps0.x = fmaf(fa, va.x, ps0.x); ps0.y = fmaf(fa, va.y, ps0.y);
        ps0.z = fmaf(fa, va.z, ps0.z); ps0.w = fmaf(fa, va.w, ps0.w);
        ps1.x = fmaf(fb, vb.x, ps1.x); ps1.y = fmaf(fb, vb.y, ps1.y);
        ps1.z = fmaf(fb, vb.z, ps1.z); ps1.w = fmaf(fb, vb.w, ps1.w);
        ps2.x = fmaf(fc, vc.x, ps2.x); ps2.y = fmaf(fc, vc.y, ps2.y);
        ps2.z = fmaf(fc, vc.z, ps2.z); ps2.w = fmaf(fc, vc.w, ps2.w);
        ps3.x = fmaf(fd, vd.x, ps3.x); ps3.y = fmaf(fd, vd.y, ps3.y);
        ps3.z = fmaf(fd, vd.z, ps3.z); ps3.w = fmaf(fd, vd.w, ps3.w);
        L0 = fmaf(fa, pl[c0 + k + 0], L0);
        L1 = fmaf(fb, pl[c0 + k + 1], L1);
        L2 = fmaf(fc, pl[c0 + k + 2], L2);
        L3 = fmaf(fd, pl[c0 + k + 3], L3);
    }
    const float L   = (L0 + L1) + (L2 + L3);
    const float inv = 1.f / L;
    float4 po;
    po.x = ((ps0.x + ps1.x) + (ps2.x + ps3.x)) * inv;
    po.y = ((ps0.y + ps1.y) + (ps2.y + ps3.y)) * inv;
    po.z = ((ps0.z + ps1.z) + (ps2.z + ps3.z)) * inv;
    po.w = ((ps0.w + ps1.w) + (ps2.w + ps3.w)) * inv;
    reinterpret_cast<float4*>(out)[(size_t)b * (D_ / 4) + t] = po;
}

extern "C" void kernel_launch(void* const* d_in, const int* in_sizes, int n_in,
                              void* d_out, int out_size, void* d_ws, size_t ws_size,
                              hipStream_t stream)
{
    const float* data = (const float*)d_in[0];   // [B, S, D]
    const float* crit = (const float*)d_in[1];   // [B, D]
    float* ws   = (float*)d_ws;
    float* pm   = ws + PM_OFF;
    float* pl   = ws + PL_OFF;
    int*   cnt  = (int*)(ws + CNT_OFF);
    float* pacc = ws + PACC_OFF;
    float* out  = (float*)d_out;

    // counters must be zero at kernel start on EVERY call (ws is poisoned
    // once, never re-poisoned): stream-ordered memset node, graph-safe.
    (void)hipMemsetAsync(cnt, 0, B_ * sizeof(int), stream);
    attn_fused<<<NBLK, 256, 0, stream>>>(data, crit, pm, pl, pacc, cnt, out);
}

// Round 9
// 56.884 us; speedup vs baseline: 1.6613x; 1.6613x over previous
//
#include <hip/hip_runtime.h>
#include <math.h>

// Problem constants (from reference): B=8, S=4096, D=1024, fp32 in/out.
#define B_   8
#define S_   4096
#define D_   1024
#define RPW  16                 // rows (seq positions) per wave
#define NPB  (S_ / RPW)         // 256 partials per batch
#define NP   (B_ * NPB)         // 2048 partials total

// ws layout (float offsets)
#define PM_OFF    0                       // [NP]   per-wave local max
#define PL_OFF    (PM_OFF + NP)           // [NP]   per-wave local denom
#define PACC_OFF  16384                   // [NP * D_]   (64KB aligned)

// ---------------------------------------------------------------------------
// Pass 1: one pass over data (byte-identical to the R5 champion).
// Wave owns 16 consecutive rows of one b; lane owns 16 columns (4x float4).
// Explicit A/B register double-buffer keeps the next 4-row batch's 16
// dwordx4 loads posted during every compute phase.
//
// launch_bounds(256,2): R4/R5 A/B proved hipcc clamps to 64 VGPR without it
// (wholesale scratch spill); (256,2) grants 256 VGPRs, the ~190-reg live set
// fits. R8 lesson: do NOT add LDS-merge/fence/atomic code to this kernel --
// it pushes the allocator to the 128-VGPR tier and re-spills (-58 us).
// ---------------------------------------------------------------------------
__global__ __launch_bounds__(256, 2) void attn_pass1(
    const float* __restrict__ data, const float* __restrict__ crit,
    float* __restrict__ pm, float* __restrict__ pl, float* __restrict__ pacc)
{
    const int lane = threadIdx.x & 63;
    const int gw   = blockIdx.x * 4 + (threadIdx.x >> 6);  // 0..NP-1
    const int b    = gw >> 8;                               // / NPB (=256)
    const int pi   = gw & 255;                              // % NPB
    const int s0   = pi * RPW;

    const float4* c4p = reinterpret_cast<const float4*>(crit + (size_t)b * D_);
    float4 cc[4];
    cc[0] = c4p[0 * 64 + lane];
    cc[1] = c4p[1 * 64 + lane];
    cc[2] = c4p[2 * 64 + lane];
    cc[3] = c4p[3 * 64 + lane];

    const float4* dp = reinterpret_cast<const float4*>(data)
                     + (size_t)(b * S_ + s0) * (D_ / 4);

    float4 a0 = {0,0,0,0}, a1 = {0,0,0,0}, a2 = {0,0,0,0}, a3 = {0,0,0,0};
    float m = -INFINITY, l = 0.f;

    float4 vA[4][4], vB[4][4];

    #define LOADG(V, G)                                                        \
        {                                                                      \
            _Pragma("unroll")                                                  \
            for (int r = 0; r < 4; ++r) {                                      \
                const float4* rp = dp + (size_t)((G) * 4 + r) * (D_ / 4);      \
                V[r][0] = rp[0 * 64 + lane];                                   \
                V[r][1] = rp[1 * 64 + lane];                                   \
                V[r][2] = rp[2 * 64 + lane];                                   \
                V[r][3] = rp[3 * 64 + lane];                                   \
            }                                                                  \
        }

    // Accumulator update: direct named variables, compile-time fields only
    // (R3 lesson: no pointers-to-local -> no blocked SROA).
    #define UPD1(A, V, J, F)                                                   \
        A.F = fmaf(A.F, scale, fmaf(p0, V[0][J].F, fmaf(p1, V[1][J].F,         \
              fmaf(p2, V[2][J].F, p3 * V[3][J].F))));
    #define UPDA(A, V, J)                                                      \
        UPD1(A, V, J, x) UPD1(A, V, J, y) UPD1(A, V, J, z) UPD1(A, V, J, w)

    // COMPUTE: dot -> pack-4 cross-lane reduce (11 DS ops) -> online softmax.
    #define COMPUTE(V)                                                         \
        {                                                                      \
            float sc[4];                                                       \
            _Pragma("unroll")                                                  \
            for (int r = 0; r < 4; ++r) {                                      \
                float p = 0.f;                                                 \
                _Pragma("unroll")                                              \
                for (int j = 0; j < 4; ++j) {                                  \
                    p = fmaf(V[r][j].x, cc[j].x, p);                           \
                    p = fmaf(V[r][j].y, cc[j].y, p);                           \
                    p = fmaf(V[r][j].z, cc[j].z, p);                           \
                    p = fmaf(V[r][j].w, cc[j].w, p);                           \
                }                                                              \
                sc[r] = p;                                                     \
            }                                                                  \
            const bool o1 = (lane & 1);                                        \
            float v01 = o1 ? sc[1] : sc[0], w01 = o1 ? sc[0] : sc[1];          \
            float v23 = o1 ? sc[3] : sc[2], w23 = o1 ? sc[2] : sc[3];          \
            v01 += __shfl_xor(w01, 1, 64);                                     \
            v23 += __shfl_xor(w23, 1, 64);                                     \
            const bool o2 = (lane & 2);                                        \
            float av = o2 ? v23 : v01, bv = o2 ? v01 : v23;                    \
            av += __shfl_xor(bv, 2, 64);                                       \
            av += __shfl_xor(av, 4, 64);                                       \
            av += __shfl_xor(av, 8, 64);                                       \
            av += __shfl_xor(av, 16, 64);                                      \
            av += __shfl_xor(av, 32, 64);                                      \
            const int base = lane & ~3;                                        \
            const float s0v = __shfl(av, base + 0, 64);                        \
            const float s1v = __shfl(av, base + 1, 64);                        \
            const float s2v = __shfl(av, base + 2, 64);                        \
            const float s3v = __shfl(av, base + 3, 64);                        \
            const float gm = fmaxf(fmaxf(s0v, s1v), fmaxf(s2v, s3v));          \
            const float mn = fmaxf(m, gm);                                     \
            const float scale = __expf(m - mn);                                \
            const float p0 = __expf(s0v - mn);                                 \
            const float p1 = __expf(s1v - mn);                                 \
            const float p2 = __expf(s2v - mn);                                 \
            const float p3 = __expf(s3v - mn);                                 \
            l = fmaf(l, scale, p0 + p1 + p2 + p3);                             \
            UPDA(a0, V, 0) UPDA(a1, V, 1) UPDA(a2, V, 2) UPDA(a3, V, 3)        \
            m = mn;                                                            \
        }

    // Software pipeline over the 4 groups: next batch's loads always posted.
    LOADG(vA, 0)
    LOADG(vB, 1)
    COMPUTE(vA)
    LOADG(vA, 2)
    COMPUTE(vB)
    LOADG(vB, 3)
    COMPUTE(vA)
    COMPUTE(vB)

    #undef LOADG
    #undef COMPUTE
    #undef UPDA
    #undef UPD1

    float4* po = reinterpret_cast<float4*>(pacc) + (size_t)gw * (D_ / 4);
    po[0 * 64 + lane] = a0;
    po[1 * 64 + lane] = a1;
    po[2 * 64 + lane] = a2;
    po[3 * 64 + lane] = a3;
    if (lane == 0) { pm[gw] = m; pl[gw] = l; }
}

// ---------------------------------------------------------------------------
// Combine (single kernel): block (slice g, batch b); thread owns ONE column
// col = g*256 + t. Redundantly computes m* over the batch's 256 pm (tiny,
// L2-hot), then a fixed-order rescaled sum over all 256 partials.
// Deterministic: fixed set, fixed order.
// ---------------------------------------------------------------------------
__global__ __launch_bounds__(256) void attn_combine(
    const float* __restrict__ pm, const float* __restrict__ pl,
    const float* __restrict__ pacc, float* __restrict__ out)
{
    const int b   = blockIdx.y;
    const int col = blockIdx.x * 256 + threadIdx.x;   // 0..1023
    const int c0  = b * NPB;

    float mstar = -INFINITY;
    #pragma unroll 8
    for (int k = 0; k < NPB; ++k) mstar = fmaxf(mstar, pm[c0 + k]);

    float s0 = 0.f, s1 = 0.f, s2 = 0.f, s3 = 0.f;
    float L0 = 0.f, L1 = 0.f, L2 = 0.f, L3 = 0.f;
    #pragma unroll 4
    for (int k = 0; k < NPB; k += 4) {
        const float fa = __expf(pm[c0 + k + 0] - mstar);
        const float fb = __expf(pm[c0 + k + 1] - mstar);
        const float fc = __expf(pm[c0 + k + 2] - mstar);
        const float fd = __expf(pm[c0 + k + 3] - mstar);
        s0 = fmaf(fa, pacc[(size_t)(c0 + k + 0) * D_ + col], s0);
        s1 = fmaf(fb, pacc[(size_t)(c0 + k + 1) * D_ + col], s1);
        s2 = fmaf(fc, pacc[(size_t)(c0 + k + 2) * D_ + col], s2);
        s3 = fmaf(fd, pacc[(size_t)(c0 + k + 3) * D_ + col], s3);
        L0 = fmaf(fa, pl[c0 + k + 0], L0);
        L1 = fmaf(fb, pl[c0 + k + 1], L1);
        L2 = fmaf(fc, pl[c0 + k + 2], L2);
        L3 = fmaf(fd, pl[c0 + k + 3], L3);
    }
    const float L = (L0 + L1) + (L2 + L3);
    out[(size_t)b * D_ + col] = ((s0 + s1) + (s2 + s3)) / L;
}

extern "C" void kernel_launch(void* const* d_in, const int* in_sizes, int n_in,
                              void* d_out, int out_size, void* d_ws, size_t ws_size,
                              hipStream_t stream)
{
    const float* data = (const float*)d_in[0];   // [B, S, D]
    const float* crit = (const float*)d_in[1];   // [B, D]
    float* ws   = (float*)d_ws;
    float* pm   = ws + PM_OFF;
    float* pl   = ws + PL_OFF;
    float* pacc = ws + PACC_OFF;
    float* out  = (float*)d_out;

    attn_pass1 <<<NP / 4, 256, 0, stream>>>(data, crit, pm, pl, pacc);
    attn_combine<<<dim3(D_ / 256, B_), 256, 0, stream>>>(pm, pl, pacc, out);
}

// Round 10
// 37.338 us; speedup vs baseline: 2.5309x; 1.5235x over previous
//
#include <hip/hip_runtime.h>
#include <math.h>

// Problem constants (from reference): B=8, S=4096, D=1024, fp32 in/out.
#define B_   8
#define S_   4096
#define D_   1024
#define RPW  16                 // rows (seq positions) per wave
#define NPB  (S_ / RPW)         // 256 partials per batch
#define NP   (B_ * NPB)         // 2048 partials total

// ws layout (float offsets)
#define PM_OFF    0                       // [NP]   per-wave local max
#define PL_OFF    (PM_OFF + NP)           // [NP]   per-wave local denom
#define PACC_OFF  16384                   // [NP * D_]   (64KB aligned)

// ---------------------------------------------------------------------------
// Pass 1: one pass over data (byte-identical to the R5 champion, 36.7us).
// Wave owns 16 consecutive rows of one b; lane owns 16 columns (4x float4).
// Explicit A/B register double-buffer keeps the next 4-row batch's 16
// dwordx4 loads posted during every compute phase.
//
// launch_bounds(256,2): R4/R5 A/B proved hipcc clamps to 64 VGPR without it
// (wholesale scratch spill); (256,2) grants 256 VGPRs, the ~190-reg live set
// fits. R8 lesson: do NOT add LDS/fence/atomic code here (128-VGPR re-spill).
// ---------------------------------------------------------------------------
__global__ __launch_bounds__(256, 2) void attn_pass1(
    const float* __restrict__ data, const float* __restrict__ crit,
    float* __restrict__ pm, float* __restrict__ pl, float* __restrict__ pacc)
{
    const int lane = threadIdx.x & 63;
    const int gw   = blockIdx.x * 4 + (threadIdx.x >> 6);  // 0..NP-1
    const int b    = gw >> 8;                               // / NPB (=256)
    const int pi   = gw & 255;                              // % NPB
    const int s0   = pi * RPW;

    const float4* c4p = reinterpret_cast<const float4*>(crit + (size_t)b * D_);
    float4 cc[4];
    cc[0] = c4p[0 * 64 + lane];
    cc[1] = c4p[1 * 64 + lane];
    cc[2] = c4p[2 * 64 + lane];
    cc[3] = c4p[3 * 64 + lane];

    const float4* dp = reinterpret_cast<const float4*>(data)
                     + (size_t)(b * S_ + s0) * (D_ / 4);

    float4 a0 = {0,0,0,0}, a1 = {0,0,0,0}, a2 = {0,0,0,0}, a3 = {0,0,0,0};
    float m = -INFINITY, l = 0.f;

    float4 vA[4][4], vB[4][4];

    #define LOADG(V, G)                                                        \
        {                                                                      \
            _Pragma("unroll")                                                  \
            for (int r = 0; r < 4; ++r) {                                      \
                const float4* rp = dp + (size_t)((G) * 4 + r) * (D_ / 4);      \
                V[r][0] = rp[0 * 64 + lane];                                   \
                V[r][1] = rp[1 * 64 + lane];                                   \
                V[r][2] = rp[2 * 64 + lane];                                   \
                V[r][3] = rp[3 * 64 + lane];                                   \
            }                                                                  \
        }

    // Accumulator update: direct named variables, compile-time fields only
    // (R3 lesson: no pointers-to-local -> no blocked SROA).
    #define UPD1(A, V, J, F)                                                   \
        A.F = fmaf(A.F, scale, fmaf(p0, V[0][J].F, fmaf(p1, V[1][J].F,         \
              fmaf(p2, V[2][J].F, p3 * V[3][J].F))));
    #define UPDA(A, V, J)                                                      \
        UPD1(A, V, J, x) UPD1(A, V, J, y) UPD1(A, V, J, z) UPD1(A, V, J, w)

    // COMPUTE: dot -> pack-4 cross-lane reduce (11 DS ops) -> online softmax.
    #define COMPUTE(V)                                                         \
        {                                                                      \
            float sc[4];                                                       \
            _Pragma("unroll")                                                  \
            for (int r = 0; r < 4; ++r) {                                      \
                float p = 0.f;                                                 \
                _Pragma("unroll")                                              \
                for (int j = 0; j < 4; ++j) {                                  \
                    p = fmaf(V[r][j].x, cc[j].x, p);                           \
                    p = fmaf(V[r][j].y, cc[j].y, p);                           \
                    p = fmaf(V[r][j].z, cc[j].z, p);                           \
                    p = fmaf(V[r][j].w, cc[j].w, p);                           \
                }                                                              \
                sc[r] = p;                                                     \
            }                                                                  \
            const bool o1 = (lane & 1);                                        \
            float v01 = o1 ? sc[1] : sc[0], w01 = o1 ? sc[0] : sc[1];          \
            float v23 = o1 ? sc[3] : sc[2], w23 = o1 ? sc[2] : sc[3];          \
            v01 += __shfl_xor(w01, 1, 64);                                     \
            v23 += __shfl_xor(w23, 1, 64);                                     \
            const bool o2 = (lane & 2);                                        \
            float av = o2 ? v23 : v01, bv = o2 ? v01 : v23;                    \
            av += __shfl_xor(bv, 2, 64);                                       \
            av += __shfl_xor(av, 4, 64);                                       \
            av += __shfl_xor(av, 8, 64);                                       \
            av += __shfl_xor(av, 16, 64);                                      \
            av += __shfl_xor(av, 32, 64);                                      \
            const int base = lane & ~3;                                        \
            const float s0v = __shfl(av, base + 0, 64);                        \
            const float s1v = __shfl(av, base + 1, 64);                        \
            const float s2v = __shfl(av, base + 2, 64);                        \
            const float s3v = __shfl(av, base + 3, 64);                        \
            const float gm = fmaxf(fmaxf(s0v, s1v), fmaxf(s2v, s3v));          \
            const float mn = fmaxf(m, gm);                                     \
            const float scale = __expf(m - mn);                                \
            const float p0 = __expf(s0v - mn);                                 \
            const float p1 = __expf(s1v - mn);                                 \
            const float p2 = __expf(s2v - mn);                                 \
            const float p3 = __expf(s3v - mn);                                 \
            l = fmaf(l, scale, p0 + p1 + p2 + p3);                             \
            UPDA(a0, V, 0) UPDA(a1, V, 1) UPDA(a2, V, 2) UPDA(a3, V, 3)        \
            m = mn;                                                            \
        }

    // Software pipeline over the 4 groups: next batch's loads always posted.
    LOADG(vA, 0)
    LOADG(vB, 1)
    COMPUTE(vA)
    LOADG(vA, 2)
    COMPUTE(vB)
    LOADG(vB, 3)
    COMPUTE(vA)
    COMPUTE(vB)

    #undef LOADG
    #undef COMPUTE
    #undef UPDA
    #undef UPD1

    float4* po = reinterpret_cast<float4*>(pacc) + (size_t)gw * (D_ / 4);
    po[0 * 64 + lane] = a0;
    po[1 * 64 + lane] = a1;
    po[2 * 64 + lane] = a2;
    po[3 * 64 + lane] = a3;
    if (lane == 0) { pm[gw] = m; pl[gw] = l; }
}

// ---------------------------------------------------------------------------
// Combine (single kernel, R9 lesson applied): block = (256-col slice, b).
// The 4 waves SPLIT the 256 partials (64 each); lane owns ONE float4 column
// -> 64 dwordx4 loads per thread (1KB/wave/instr, same width as R5's
// combine1), not 256 scalar loads. pm/pl staged in LDS; mstar and L via
// fixed-tree block reductions; 4-wave acc merge in LDS. All reduction
// orders fixed -> deterministic.
// ---------------------------------------------------------------------------
__global__ __launch_bounds__(256) void attn_combine(
    const float* __restrict__ pm, const float* __restrict__ pl,
    const float* __restrict__ pacc, float* __restrict__ out)
{
    const int b     = blockIdx.y;
    const int slice = blockIdx.x;            // 0..3, covers cols slice*256..+255
    const int t     = threadIdx.x;           // 0..255
    const int wid   = t >> 6;                // wave 0..3
    const int lane  = t & 63;
    const int c0    = b * NPB;

    __shared__ float  lds_pm[NPB];
    __shared__ float  lds_pl[NPB];
    __shared__ float  red[256];
    __shared__ float4 lds_acc[4][64];
    __shared__ float  lds_mstar, lds_L;

    // stage pm/pl (one load per thread each)
    lds_pm[t] = pm[c0 + t];
    lds_pl[t] = pl[c0 + t];
    __syncthreads();

    // block max over 256 pm values (fixed tree)
    red[t] = lds_pm[t];
    __syncthreads();
    #pragma unroll
    for (int s = 128; s > 0; s >>= 1) {
        if (t < s) red[t] = fmaxf(red[t], red[t + s]);
        __syncthreads();
    }
    if (t == 0) lds_mstar = red[0];
    __syncthreads();
    const float mstar = lds_mstar;

    // block sum of f_k * pl_k (fixed tree)
    red[t] = __expf(lds_pm[t] - mstar) * lds_pl[t];
    __syncthreads();
    #pragma unroll
    for (int s = 128; s > 0; s >>= 1) {
        if (t < s) red[t] = red[t] + red[t + s];
        __syncthreads();
    }
    if (t == 0) lds_L = red[0];
    __syncthreads();
    const float inv = 1.f / lds_L;

    // wave wid accumulates k = wid*64 .. wid*64+63 for its float4 column
    const int col4 = slice * 64 + lane;       // float4 index within the row
    const float4* pa4 = reinterpret_cast<const float4*>(pacc);
    float4 acc = {0, 0, 0, 0};
    #pragma unroll 8
    for (int k = 0; k < 64; ++k) {
        const int kk = wid * 64 + k;
        const float f = __expf(lds_pm[kk] - mstar);
        const float4 v = pa4[(size_t)(c0 + kk) * (D_ / 4) + col4];
        acc.x = fmaf(f, v.x, acc.x);
        acc.y = fmaf(f, v.y, acc.y);
        acc.z = fmaf(f, v.z, acc.z);
        acc.w = fmaf(f, v.w, acc.w);
    }
    lds_acc[wid][lane] = acc;
    __syncthreads();

    // first 64 threads merge the 4 waves (fixed order) and write out
    if (t < 64) {
        const float4 q0 = lds_acc[0][t];
        const float4 q1 = lds_acc[1][t];
        const float4 q2 = lds_acc[2][t];
        const float4 q3 = lds_acc[3][t];
        float4 o;
        o.x = ((q0.x + q1.x) + (q2.x + q3.x)) * inv;
        o.y = ((q0.y + q1.y) + (q2.y + q3.y)) * inv;
        o.z = ((q0.z + q1.z) + (q2.z + q3.z)) * inv;
        o.w = ((q0.w + q1.w) + (q2.w + q3.w)) * inv;
        reinterpret_cast<float4*>(out)[(size_t)b * (D_ / 4) + slice * 64 + t] = o;
    }
}

extern "C" void kernel_launch(void* const* d_in, const int* in_sizes, int n_in,
                              void* d_out, int out_size, void* d_ws, size_t ws_size,
                              hipStream_t stream)
{
    const float* data = (const float*)d_in[0];   // [B, S, D]
    const float* crit = (const float*)d_in[1];   // [B, D]
    float* ws   = (float*)d_ws;
    float* pm   = ws + PM_OFF;
    float* pl   = ws + PL_OFF;
    float* pacc = ws + PACC_OFF;
    float* out  = (float*)d_out;

    attn_pass1  <<<NP / 4, 256, 0, stream>>>(data, crit, pm, pl, pacc);
    attn_combine<<<dim3(D_ / 256, B_), 256, 0, stream>>>(pm, pl, pacc, out);
}